// Round 9
// baseline (63.681 us; speedup 1.0000x reference)
//
#include <hip/hip_runtime.h>
#include <math.h>

typedef __attribute__((ext_vector_type(8))) short short8;
typedef __attribute__((ext_vector_type(4))) float f32x4;

#define BB 1024
#define DD 64
#define NPIX (1024*3*64*64)

#define LN2PI_F  1.8378770664093453f   // ln(2*pi)
#define LOG2E_F  1.4426950408889634f

#define INV_M  (1.0f/1023.0f)
#define INV_N  (1.0f/50000.0f)
#define STRATF ((float)((50000.0-1023.0)/(50000.0*1023.0)))
#define NEGBIG (-3.0e38f)

// log2 importance weights
#define L2_INVM  (-9.9985904f)    // -log2(1023)
#define L2_INVN  (-15.6096405f)   // -log2(50000)
#define L2_STRAT (-10.0284195f)   // log2(STRATF)

// ws layout (float offsets)
#define WS_RP    0         // 1536 recon partials (3 chunks x 512)
#define WS_LQC   2048      // 1024
#define WS_LPZ   3072      // 1024
#define WS_LQZ   4096      // 1024
#define WS_LPR   5120      // 1024
#define WS_Z     6144      // 65536
#define WS_Z2    71680     // 65536
#define WS_A     137216    // 65536
#define WS_B     202752    // 65536
#define WS_C     268288    // 65536
#define WS_KC    333824    // 1024
#define WS_QZP   334848    // 32*1024*2 = 65536
#define WS_ABF   924672    // bf16 A (1024x128 ushort)
#define WS_BBF   990208    // bf16 B

// recon pipeline: 3 chunks x 512 blocks; each chunk = 1048576 float4s
// = 131072 threads x 8 reps. Total = 3145728 = NPIX/4 exactly.
#define RECON_CHUNK_BLOCKS 512
#define RECON_CHUNK_F4     1048576
#define RECON_CHUNK_THREADS (RECON_CHUNK_BLOCKS*256)
#define RECON_REPS 8

#define NB_PREP   256
#define NB_MM     256
#define NB_SEDF   128   // full-j sed blocks, fused -> LPR
#define NB_POSTQZ 256

__device__ __forceinline__ float fexp2(float x){ return __builtin_amdgcn_exp2f(x); }
__device__ __forceinline__ float flog2(float x){ return __builtin_amdgcn_logf(x); }
__device__ __forceinline__ unsigned short tobf(float f){
    unsigned int u = __float_as_uint(f);
    u = (u + 0x7FFFu + ((u >> 16) & 1u)) >> 16;
    return (unsigned short)u;
}
// Agent-scope relaxed load -> global_load_dwordx2 sc0 (L1 bypass). Proven +6%
// (round 7). Read path caps ~2.8-2.9 TB/s regardless of variant (rounds 4-8).
__device__ __forceinline__ unsigned long long ld_agent(const unsigned long long* p) {
    return __hip_atomic_load(p, __ATOMIC_RELAXED, __HIP_MEMORY_SCOPE_AGENT);
}

// ---------------- building blocks ----------------
__device__ __forceinline__ void do_recon(int chunk, int lb, int t,
                                         const unsigned long long* rp,
                                         const unsigned long long* xp,
                                         float* __restrict__ ws,
                                         float* __restrict__ red) {
    long long base4 = (long long)chunk * RECON_CHUNK_F4 + lb * 256 + t;
    float acc = 0.f;
    #pragma unroll
    for (int rep = 0; rep < RECON_REPS; rep++) {
        long long i2 = 2LL * (base4 + rep * RECON_CHUNK_THREADS);
        unsigned long long a0 = ld_agent(rp + i2);
        unsigned long long a1 = ld_agent(rp + i2 + 1);
        unsigned long long b0 = ld_agent(xp + i2);
        unsigned long long b1 = ld_agent(xp + i2 + 1);
        float d0 = __uint_as_float((unsigned)a0)         - __uint_as_float((unsigned)b0);
        float d1 = __uint_as_float((unsigned)(a0 >> 32)) - __uint_as_float((unsigned)(b0 >> 32));
        float d2 = __uint_as_float((unsigned)a1)         - __uint_as_float((unsigned)b1);
        float d3 = __uint_as_float((unsigned)(a1 >> 32)) - __uint_as_float((unsigned)(b1 >> 32));
        acc = fmaf(d0, d0, acc); acc = fmaf(d1, d1, acc);
        acc = fmaf(d2, d2, acc); acc = fmaf(d3, d3, acc);
    }
    red[t] = acc; __syncthreads();
    for (int o = 128; o > 0; o >>= 1) {
        if (t < o) red[t] += red[t + o];
        __syncthreads();
    }
    if (t == 0) ws[WS_RP + chunk * RECON_CHUNK_BLOCKS + lb] = red[0];
}

__device__ __forceinline__ void do_prep(int pb, int t,
                                        const float* __restrict__ mu,
                                        const float* __restrict__ logvar,
                                        const float* __restrict__ noise,
                                        float* __restrict__ ws) {
    int d = t & 63, w = t >> 6;
    int i = pb * 4 + w;
    int idx = i * 64 + d;
    float m = mu[idx], lvv = logvar[idx], n = noise[idx];
    float sh   = fexp2(0.5f * LOG2E_F * lvv);        // e^{lv/2}
    float z    = fmaf(n, sh, m);
    float eneg = fexp2(-LOG2E_F * lvv);              // e^{-lv}
    float a = -0.5f * LOG2E_F * eneg;
    float b = -2.0f * a * m;
    float c = fmaf(a, m * m, -0.5f * LOG2E_F * (LN2PI_F + lvv));
    float z2 = z * z;
    ws[WS_Z  + idx] = z;  ws[WS_Z2 + idx] = z2;
    ws[WS_A  + idx] = a;  ws[WS_B  + idx] = b;  ws[WS_C + idx] = c;
    unsigned short* abf = (unsigned short*)(ws + WS_ABF);
    unsigned short* bbf = (unsigned short*)(ws + WS_BBF);
    abf[i * 128 + d]      = tobf(z2);
    abf[i * 128 + 64 + d] = tobf(z);
    bbf[i * 128 + d]      = tobf(a);
    bbf[i * 128 + 64 + d] = tobf(b);
    float lqc = -0.5f * (LN2PI_F + lvv + n * n);
    float lpz = -0.5f * (LN2PI_F + z2);
    float kc  = c;
    for (int off = 32; off > 0; off >>= 1) {
        lqc += __shfl_xor(lqc, off, 64);
        lpz += __shfl_xor(lpz, off, 64);
        kc  += __shfl_xor(kc,  off, 64);
    }
    if (d == 0) { ws[WS_LQC + i] = lqc; ws[WS_LPZ + i] = lpz; ws[WS_KC + i] = kc; }
}

__device__ __forceinline__ void do_mm(int mmid, int t, float* __restrict__ ws) {
    int lane = t & 63, w = t >> 6;
    const unsigned short* abf = (const unsigned short*)(ws + WS_ABF);
    const unsigned short* bbf = (const unsigned short*)(ws + WS_BBF);
    int i0 = (mmid & 15) * 64, j0 = (mmid >> 4) * 64;
    int lo = lane & 15, g = lane >> 4;
    int wi = (w >> 1) * 32, wj = (w & 1) * 32;
    f32x4 acc[2][2] = {};
    #pragma unroll
    for (int kk = 0; kk < 4; kk++) {
        short8 af[2], bfr[2];
        #pragma unroll
        for (int fy = 0; fy < 2; fy++)
            af[fy] = *(const short8*)&abf[(i0 + wi + fy * 16 + lo) * 128 + (kk * 4 + g) * 8];
        #pragma unroll
        for (int fx = 0; fx < 2; fx++)
            bfr[fx] = *(const short8*)&bbf[(j0 + wj + fx * 16 + lo) * 128 + (kk * 4 + g) * 8];
        #pragma unroll
        for (int fy = 0; fy < 2; fy++)
            #pragma unroll
            for (int fx = 0; fx < 2; fx++)
                acc[fy][fx] = __builtin_amdgcn_mfma_f32_16x16x32_bf16(af[fy], bfr[fx], acc[fy][fx], 0, 0, 0);
    }
    int jA = j0 + wj + lo;
    float kcv0 = ws[WS_KC + jA], kcv1 = ws[WS_KC + jA + 16];
    int pc = (j0 >> 5) + (w & 1);
    #pragma unroll
    for (int fy = 0; fy < 2; fy++) {
        #pragma unroll
        for (int r = 0; r < 4; r++) {
            int i = i0 + wi + fy * 16 + g * 4 + r;
            float vv0, vv1;
            {
                int j = jA;
                float lw = (j == 1) ? L2_STRAT : (i == j) ? L2_INVN
                         : (i == 1022 && j == 0) ? L2_STRAT : L2_INVM;
                vv0 = acc[fy][0][r] + kcv0 + 64.0f * lw;
            }
            {
                int j = jA + 16;
                float lw = (j == 1) ? L2_STRAT : (i == j) ? L2_INVN
                         : (i == 1022 && j == 0) ? L2_STRAT : L2_INVM;
                vv1 = acc[fy][1][r] + kcv1 + 64.0f * lw;
            }
            float m = fmaxf(vv0, vv1);
            float s = fexp2(vv0 - m) + fexp2(vv1 - m);
            for (int off = 1; off < 16; off <<= 1) {
                float om = __shfl_xor(m, off, 64);
                float os = __shfl_xor(s, off, 64);
                float M = fmaxf(m, om);
                s = s * fexp2(m - M) + os * fexp2(om - M);
                m = M;
            }
            if (lo == 0) {
                ws[WS_QZP + ((pc << 10) + i) * 2]     = m;
                ws[WS_QZP + ((pc << 10) + i) * 2 + 1] = s;
            }
        }
    }
}

// sed over FULL j range (1024), fused weights+log -> LPR. 128 blocks x 8 rows.
__device__ __forceinline__ void do_sedfull(int sid, int t, float* __restrict__ ws,
                                           float* __restrict__ sacc) {
    int lane = t & 63, w = t >> 6;
    int i0 = sid * 8, d = lane;
    int jbase = w * 256;                 // each wave covers 256 consecutive j
    const float* Ap = ws + WS_A;
    const float* Bp = ws + WS_B;
    const float* Cp = ws + WS_C;
    float z2r[8], zr[8], se[8];
    #pragma unroll
    for (int k = 0; k < 8; k++) {
        z2r[k] = ws[WS_Z2 + (i0 + k) * 64 + d];
        zr[k]  = ws[WS_Z  + (i0 + k) * 64 + d];
        se[k] = 0.f;
    }
    float aP[8], bP[8], cP[8], aQ[8], bQ[8], cQ[8];
    #pragma unroll
    for (int u = 0; u < 8; u++) {
        int gg = (jbase + u) * 64 + d;
        aP[u] = Ap[gg]; bP[u] = Bp[gg]; cP[u] = Cp[gg];
    }
    for (int batch = 0; batch < 32; batch++) {
        if (batch < 31) {
            #pragma unroll
            for (int u = 0; u < 8; u++) {
                int gg = (jbase + (batch + 1) * 8 + u) * 64 + d;
                aQ[u] = Ap[gg]; bQ[u] = Bp[gg]; cQ[u] = Cp[gg];
            }
        }
        #pragma unroll
        for (int u = 0; u < 8; u++) {
            #pragma unroll
            for (int k = 0; k < 8; k++) {
                float uu = fmaf(aP[u], z2r[k], fmaf(bP[u], zr[k], cP[u]));
                se[k] += fexp2(uu);
            }
        }
        if (batch < 31) {
            #pragma unroll
            for (int u = 0; u < 8; u++) { aP[u] = aQ[u]; bP[u] = bQ[u]; cP[u] = cQ[u]; }
        }
    }
    #pragma unroll
    for (int k = 0; k < 8; k++) sacc[w * 512 + k * 64 + d] = se[k];
    __syncthreads();
    // fused epilogue: each wave owns rows k = w*2, w*2+1
    #pragma unroll
    for (int kq = 0; kq < 2; kq++) {
        int k = w * 2 + kq;
        int i = i0 + k;
        float tot = sacc[k * 64 + d] + sacc[512 + k * 64 + d]
                  + sacc[1024 + k * 64 + d] + sacc[1536 + k * 64 + d];
        float z2 = z2r[k], z = zr[k];
        auto E = [&](int j) -> float {
            int gidx = j * 64 + d;
            return fexp2(fmaf(Ap[gidx], z2, fmaf(Bp[gidx], z, Cp[gidx])));
        };
        float sidv = INV_M * tot;
        if (i != 1)    sidv += (INV_N  - INV_M) * E(i);
        sidv += (STRATF - INV_M) * E(1);
        if (i == 1022) sidv += (STRATF - INV_M) * E(0);
        float lg = flog2(sidv);
        for (int off = 1; off < 64; off <<= 1) lg += __shfl_xor(lg, off, 64);
        if (d == 0) ws[WS_LPR + i] = lg * (1.0f / LOG2E_F);
    }
}

// combine 32 QZP chunk partials -> LQZ
__device__ __forceinline__ void do_postqz(int pb, int t, float* __restrict__ ws) {
    int lane = t & 63, w = t >> 6;
    int i = pb * 4 + w;
    float m = NEGBIG, s = 0.f;
    if (lane < 32) {
        m = ws[WS_QZP + ((lane << 10) + i) * 2];
        s = ws[WS_QZP + ((lane << 10) + i) * 2 + 1];
    }
    for (int off = 1; off < 64; off <<= 1) {
        float om = __shfl_xor(m, off, 64);
        float os = __shfl_xor(s, off, 64);
        float M = fmaxf(m, om);
        s = s * fexp2(m - M) + os * fexp2(om - M);
        m = M;
    }
    if (lane == 0) ws[WS_LQZ + i] = (m + flog2(s)) * (1.0f / LOG2E_F);
}

// ---------------- dispatch 1: prep || recon chunk0 ----------------
__global__ __launch_bounds__(256) void k_d1(const float* __restrict__ rx,
                                            const float* __restrict__ x,
                                            const float* __restrict__ mu,
                                            const float* __restrict__ logvar,
                                            const float* __restrict__ noise,
                                            float* __restrict__ ws) {
    __shared__ float smem[256];
    int bid = blockIdx.x, t = threadIdx.x;
    if (bid < NB_PREP)
        do_prep(bid, t, mu, logvar, noise, ws);
    else
        do_recon(0, bid - NB_PREP, t, (const unsigned long long*)rx, (const unsigned long long*)x, ws, smem);
}

// ---------------- dispatch 2: mm || sedfull || recon chunk1 ----------------
__global__ __launch_bounds__(256) void k_d2(const float* __restrict__ rx,
                                            const float* __restrict__ x,
                                            float* __restrict__ ws) {
    __shared__ float smem[2048];
    int bid = blockIdx.x, t = threadIdx.x;
    if (bid < NB_MM)
        do_mm(bid, t, ws);
    else if (bid < NB_MM + NB_SEDF)
        do_sedfull(bid - NB_MM, t, ws, smem);
    else
        do_recon(1, bid - NB_MM - NB_SEDF, t, (const unsigned long long*)rx, (const unsigned long long*)x, ws, smem);
}

// ---------------- dispatch 3: postqz || recon chunk2 ----------------
__global__ __launch_bounds__(256) void k_d3(const float* __restrict__ rx,
                                            const float* __restrict__ x,
                                            float* __restrict__ ws) {
    __shared__ float smem[256];
    int bid = blockIdx.x, t = threadIdx.x;
    if (bid < NB_POSTQZ)
        do_postqz(bid, t, ws);
    else
        do_recon(2, bid - NB_POSTQZ, t, (const unsigned long long*)rx, (const unsigned long long*)x, ws, smem);
}

// ---------------- dispatch 4: final combine (1 block) ----------------
__global__ __launch_bounds__(256) void k_final(const float* __restrict__ ws,
                                               float* __restrict__ out) {
    int t = threadIdx.x;
    float a0 = 0, a1 = 0, a2 = 0, a3 = 0, a4 = 0;
    for (int idx = t; idx < 1536; idx += 256) a0 += ws[WS_RP + idx];
    for (int idx = t; idx < BB; idx += 256) {
        a1 += ws[WS_LQC + idx];
        a2 += ws[WS_LPZ + idx];
        a3 += ws[WS_LQZ + idx];
        a4 += ws[WS_LPR + idx];
    }
    __shared__ float red[256];
    float vals[5] = {a0, a1, a2, a3, a4};
    float res[5];
    for (int q = 0; q < 5; q++) {
        red[t] = vals[q]; __syncthreads();
        for (int o = 128; o > 0; o >>= 1) {
            if (t < o) red[t] += red[t + o];
            __syncthreads();
        }
        res[q] = red[0]; __syncthreads();
    }
    if (t == 0) {
        float recon = res[0], slqc = res[1], slpz = res[2], slqz = res[3], slpr = res[4];
        out[0] = recon + (slqc + 5.f * (slqz - slpr) - slpz) * (1.0f / (float)BB);
    }
}

extern "C" void kernel_launch(void* const* d_in, const int* in_sizes, int n_in,
                              void* d_out, int out_size, void* d_ws, size_t ws_size,
                              hipStream_t stream) {
    (void)in_sizes; (void)n_in; (void)out_size; (void)ws_size;
    const float* rx = (const float*)d_in[0];
    const float* x  = (const float*)d_in[1];
    const float* mu = (const float*)d_in[2];
    const float* lv = (const float*)d_in[3];
    const float* nz = (const float*)d_in[4];
    float* ws  = (float*)d_ws;
    float* out = (float*)d_out;

    k_d1   <<<NB_PREP + RECON_CHUNK_BLOCKS,            256, 0, stream>>>(rx, x, mu, lv, nz, ws);
    k_d2   <<<NB_MM + NB_SEDF + RECON_CHUNK_BLOCKS,    256, 0, stream>>>(rx, x, ws);
    k_d3   <<<NB_POSTQZ + RECON_CHUNK_BLOCKS,          256, 0, stream>>>(rx, x, ws);
    k_final<<<1, 256, 0, stream>>>(ws, out);
}

// Round 10
// 45.127 us; speedup vs baseline: 1.4112x; 1.4112x over previous
//
#include <hip/hip_runtime.h>
#include <math.h>

typedef __attribute__((ext_vector_type(8))) short short8;
typedef __attribute__((ext_vector_type(4))) float f32x4;

#define BB 1024
#define DD 64
#define NPIX (1024*3*64*64)

#define LN2PI_F  1.8378770664093453f   // ln(2*pi)
#define LOG2E_F  1.4426950408889634f

#define INV_M  (1.0f/1023.0f)
#define INV_N  (1.0f/50000.0f)
#define STRATF ((float)((50000.0-1023.0)/(50000.0*1023.0)))
#define NEGBIG (-3.0e38f)

// log2 importance weights
#define L2_INVM  (-9.9985904f)    // -log2(1023)
#define L2_INVN  (-15.6096405f)   // -log2(50000)
#define L2_STRAT (-10.0284195f)   // log2(STRATF)

// ws layout (float offsets)
#define WS_RP    0         // 1536 recon partials
#define WS_LQC   2048      // 1024
#define WS_LPZ   3072      // 1024
#define WS_LQZ   4096      // 1024
#define WS_LPR   5120      // 1024
#define WS_Z     6144      // 65536
#define WS_Z2    71680     // 65536
#define WS_A     137216    // 65536
#define WS_B     202752    // 65536
#define WS_C     268288    // 65536
#define WS_KC    333824    // 1024
#define WS_QZP   334848    // 32*1024*2 = 65536
#define WS_SEDP  400384    // 8*1024*64 = 524288
#define WS_ABF   924672    // bf16 A (1024x128 ushort)
#define WS_BBF   990208    // bf16 B

// recon pipeline: 3 chunks, rebalanced 560/416/560 (d2 carries mm+sed's L2
// traffic, so it gets fewer recon blocks). reps=8 each; coverage:
// 560*256*8 + 416*256*8 + 560*256*8 = 3145728 = NPIX/4 exactly.
#define C0_BLOCKS 560
#define C1_BLOCKS 416
#define C2_BLOCKS 560
#define C0_START  0
#define C1_START  1146880
#define C2_START  1998848
#define RECON_REPS 8

#define NB_PREP  256
#define NB_MM    256
#define NB_SED   1024
#define NB_POST  256

__device__ __forceinline__ float fexp2(float x){ return __builtin_amdgcn_exp2f(x); }
__device__ __forceinline__ float flog2(float x){ return __builtin_amdgcn_logf(x); }
__device__ __forceinline__ unsigned short tobf(float f){
    unsigned int u = __float_as_uint(f);
    u = (u + 0x7FFFu + ((u >> 16) & 1u)) >> 16;
    return (unsigned short)u;
}
// Agent-scope relaxed load -> global_load_dwordx2 sc0 (L1 bypass). Proven +6%
// (round 7). Read path caps ~2.9 TB/s regardless of variant (rounds 4-8).
__device__ __forceinline__ unsigned long long ld_agent(const unsigned long long* p) {
    return __hip_atomic_load(p, __ATOMIC_RELAXED, __HIP_MEMORY_SCOPE_AGENT);
}

// ---------------- building blocks ----------------
__device__ __forceinline__ void do_recon(int lb, int t,
                                         const unsigned long long* rp,
                                         const unsigned long long* xp,
                                         float* __restrict__ ws,
                                         float* __restrict__ red,
                                         long long chunkStart, int strideThreads,
                                         int rpSlot) {
    long long base4 = chunkStart + lb * 256 + t;
    float acc = 0.f;
    #pragma unroll
    for (int rep = 0; rep < RECON_REPS; rep++) {
        long long i2 = 2LL * (base4 + (long long)rep * strideThreads);
        unsigned long long a0 = ld_agent(rp + i2);
        unsigned long long a1 = ld_agent(rp + i2 + 1);
        unsigned long long b0 = ld_agent(xp + i2);
        unsigned long long b1 = ld_agent(xp + i2 + 1);
        float d0 = __uint_as_float((unsigned)a0)         - __uint_as_float((unsigned)b0);
        float d1 = __uint_as_float((unsigned)(a0 >> 32)) - __uint_as_float((unsigned)(b0 >> 32));
        float d2 = __uint_as_float((unsigned)a1)         - __uint_as_float((unsigned)b1);
        float d3 = __uint_as_float((unsigned)(a1 >> 32)) - __uint_as_float((unsigned)(b1 >> 32));
        acc = fmaf(d0, d0, acc); acc = fmaf(d1, d1, acc);
        acc = fmaf(d2, d2, acc); acc = fmaf(d3, d3, acc);
    }
    red[t] = acc; __syncthreads();
    for (int o = 128; o > 0; o >>= 1) {
        if (t < o) red[t] += red[t + o];
        __syncthreads();
    }
    if (t == 0) ws[WS_RP + rpSlot + lb] = red[0];
}

__device__ __forceinline__ void do_prep(int pb, int t,
                                        const float* __restrict__ mu,
                                        const float* __restrict__ logvar,
                                        const float* __restrict__ noise,
                                        float* __restrict__ ws) {
    int d = t & 63, w = t >> 6;
    int i = pb * 4 + w;
    int idx = i * 64 + d;
    float m = mu[idx], lvv = logvar[idx], n = noise[idx];
    float sh   = fexp2(0.5f * LOG2E_F * lvv);        // e^{lv/2}
    float z    = fmaf(n, sh, m);
    float eneg = fexp2(-LOG2E_F * lvv);              // e^{-lv}
    float a = -0.5f * LOG2E_F * eneg;
    float b = -2.0f * a * m;
    float c = fmaf(a, m * m, -0.5f * LOG2E_F * (LN2PI_F + lvv));
    float z2 = z * z;
    ws[WS_Z  + idx] = z;  ws[WS_Z2 + idx] = z2;
    ws[WS_A  + idx] = a;  ws[WS_B  + idx] = b;  ws[WS_C + idx] = c;
    unsigned short* abf = (unsigned short*)(ws + WS_ABF);
    unsigned short* bbf = (unsigned short*)(ws + WS_BBF);
    abf[i * 128 + d]      = tobf(z2);
    abf[i * 128 + 64 + d] = tobf(z);
    bbf[i * 128 + d]      = tobf(a);
    bbf[i * 128 + 64 + d] = tobf(b);
    float lqc = -0.5f * (LN2PI_F + lvv + n * n);
    float lpz = -0.5f * (LN2PI_F + z2);
    float kc  = c;
    for (int off = 32; off > 0; off >>= 1) {
        lqc += __shfl_xor(lqc, off, 64);
        lpz += __shfl_xor(lpz, off, 64);
        kc  += __shfl_xor(kc,  off, 64);
    }
    if (d == 0) { ws[WS_LQC + i] = lqc; ws[WS_LPZ + i] = lpz; ws[WS_KC + i] = kc; }
}

__device__ __forceinline__ void do_mm(int mmid, int t, float* __restrict__ ws) {
    int lane = t & 63, w = t >> 6;
    const unsigned short* abf = (const unsigned short*)(ws + WS_ABF);
    const unsigned short* bbf = (const unsigned short*)(ws + WS_BBF);
    int i0 = (mmid & 15) * 64, j0 = (mmid >> 4) * 64;
    int lo = lane & 15, g = lane >> 4;
    int wi = (w >> 1) * 32, wj = (w & 1) * 32;
    f32x4 acc[2][2] = {};
    #pragma unroll
    for (int kk = 0; kk < 4; kk++) {
        short8 af[2], bfr[2];
        #pragma unroll
        for (int fy = 0; fy < 2; fy++)
            af[fy] = *(const short8*)&abf[(i0 + wi + fy * 16 + lo) * 128 + (kk * 4 + g) * 8];
        #pragma unroll
        for (int fx = 0; fx < 2; fx++)
            bfr[fx] = *(const short8*)&bbf[(j0 + wj + fx * 16 + lo) * 128 + (kk * 4 + g) * 8];
        #pragma unroll
        for (int fy = 0; fy < 2; fy++)
            #pragma unroll
            for (int fx = 0; fx < 2; fx++)
                acc[fy][fx] = __builtin_amdgcn_mfma_f32_16x16x32_bf16(af[fy], bfr[fx], acc[fy][fx], 0, 0, 0);
    }
    int jA = j0 + wj + lo;
    float kcv0 = ws[WS_KC + jA], kcv1 = ws[WS_KC + jA + 16];
    int pc = (j0 >> 5) + (w & 1);
    #pragma unroll
    for (int fy = 0; fy < 2; fy++) {
        #pragma unroll
        for (int r = 0; r < 4; r++) {
            int i = i0 + wi + fy * 16 + g * 4 + r;
            float vv0, vv1;
            {
                int j = jA;
                float lw = (j == 1) ? L2_STRAT : (i == j) ? L2_INVN
                         : (i == 1022 && j == 0) ? L2_STRAT : L2_INVM;
                vv0 = acc[fy][0][r] + kcv0 + 64.0f * lw;
            }
            {
                int j = jA + 16;
                float lw = (j == 1) ? L2_STRAT : (i == j) ? L2_INVN
                         : (i == 1022 && j == 0) ? L2_STRAT : L2_INVM;
                vv1 = acc[fy][1][r] + kcv1 + 64.0f * lw;
            }
            float m = fmaxf(vv0, vv1);
            float s = fexp2(vv0 - m) + fexp2(vv1 - m);
            for (int off = 1; off < 16; off <<= 1) {
                float om = __shfl_xor(m, off, 64);
                float os = __shfl_xor(s, off, 64);
                float M = fmaxf(m, om);
                s = s * fexp2(m - M) + os * fexp2(om - M);
                m = M;
            }
            if (lo == 0) {
                ws[WS_QZP + ((pc << 10) + i) * 2]     = m;
                ws[WS_QZP + ((pc << 10) + i) * 2 + 1] = s;
            }
        }
    }
}

__device__ __forceinline__ void do_sed(int sid, int t, float* __restrict__ ws,
                                       float* __restrict__ sacc) {
    int lane = t & 63, w = t >> 6;
    int ic = sid & 127, jc = sid >> 7;
    int i0 = ic * 8, d = lane;
    int jbase = jc * 128 + w * 32;
    const float* Ap = ws + WS_A;
    const float* Bp = ws + WS_B;
    const float* Cp = ws + WS_C;
    float z2r[8], zr[8], se[8];
    #pragma unroll
    for (int k = 0; k < 8; k++) {
        z2r[k] = ws[WS_Z2 + (i0 + k) * 64 + d];
        zr[k]  = ws[WS_Z  + (i0 + k) * 64 + d];
        se[k] = 0.f;
    }
    float aP[8], bP[8], cP[8], aQ[8], bQ[8], cQ[8];
    #pragma unroll
    for (int u = 0; u < 8; u++) {
        int gg = (jbase + u) * 64 + d;
        aP[u] = Ap[gg]; bP[u] = Bp[gg]; cP[u] = Cp[gg];
    }
    #pragma unroll
    for (int batch = 0; batch < 4; batch++) {
        if (batch < 3) {
            #pragma unroll
            for (int u = 0; u < 8; u++) {
                int gg = (jbase + (batch + 1) * 8 + u) * 64 + d;
                aQ[u] = Ap[gg]; bQ[u] = Bp[gg]; cQ[u] = Cp[gg];
            }
        }
        #pragma unroll
        for (int u = 0; u < 8; u++) {
            #pragma unroll
            for (int k = 0; k < 8; k++) {
                float uu = fmaf(aP[u], z2r[k], fmaf(bP[u], zr[k], cP[u]));
                se[k] += fexp2(uu);
            }
        }
        if (batch < 3) {
            #pragma unroll
            for (int u = 0; u < 8; u++) { aP[u] = aQ[u]; bP[u] = bQ[u]; cP[u] = cQ[u]; }
        }
    }
    #pragma unroll
    for (int k = 0; k < 8; k++) sacc[w * 512 + k * 64 + d] = se[k];
    __syncthreads();
    int k0 = w * 2;
    for (int k = k0; k < k0 + 2; k++) {
        float tot = sacc[k * 64 + d] + sacc[512 + k * 64 + d]
                  + sacc[1024 + k * 64 + d] + sacc[1536 + k * 64 + d];
        ws[WS_SEDP + ((jc << 10) + i0 + k) * 64 + d] = tot;
    }
}

__device__ __forceinline__ void do_post(int pb, int t, float* __restrict__ ws) {
    int lane = t & 63, w = t >> 6;
    int i = pb * 4 + w;
    float m = NEGBIG, s = 0.f;
    if (lane < 32) {
        m = ws[WS_QZP + ((lane << 10) + i) * 2];
        s = ws[WS_QZP + ((lane << 10) + i) * 2 + 1];
    }
    for (int off = 1; off < 64; off <<= 1) {
        float om = __shfl_xor(m, off, 64);
        float os = __shfl_xor(s, off, 64);
        float M = fmaxf(m, om);
        s = s * fexp2(m - M) + os * fexp2(om - M);
        m = M;
    }
    if (lane == 0) ws[WS_LQZ + i] = (m + flog2(s)) * (1.0f / LOG2E_F);
    int d = lane;
    float se = 0.f;
    for (int c = 0; c < 8; c++) se += ws[WS_SEDP + ((c << 10) + i) * 64 + d];
    float z2 = ws[WS_Z2 + i * 64 + d], z = ws[WS_Z + i * 64 + d];
    auto E = [&](int j) -> float {
        int gidx = j * 64 + d;
        return fexp2(fmaf(ws[WS_A + gidx], z2, fmaf(ws[WS_B + gidx], z, ws[WS_C + gidx])));
    };
    float sid = INV_M * se;
    if (i != 1)    sid += (INV_N  - INV_M) * E(i);
    sid += (STRATF - INV_M) * E(1);
    if (i == 1022) sid += (STRATF - INV_M) * E(0);
    float lg = flog2(sid);
    for (int off = 1; off < 64; off <<= 1) lg += __shfl_xor(lg, off, 64);
    if (d == 0) ws[WS_LPR + i] = lg * (1.0f / LOG2E_F);
}

// ---------------- dispatch 1: prep || recon chunk0 ----------------
__global__ __launch_bounds__(256) void k_d1(const float* __restrict__ rx,
                                            const float* __restrict__ x,
                                            const float* __restrict__ mu,
                                            const float* __restrict__ logvar,
                                            const float* __restrict__ noise,
                                            float* __restrict__ ws) {
    __shared__ float smem[256];
    int bid = blockIdx.x, t = threadIdx.x;
    if (bid < NB_PREP)
        do_prep(bid, t, mu, logvar, noise, ws);
    else
        do_recon(bid - NB_PREP, t, (const unsigned long long*)rx,
                 (const unsigned long long*)x, ws, smem,
                 C0_START, C0_BLOCKS * 256, 0);
}

// ---------------- dispatch 2: mm || sed || recon chunk1 ----------------
__global__ __launch_bounds__(256) void k_d2(const float* __restrict__ rx,
                                            const float* __restrict__ x,
                                            float* __restrict__ ws) {
    __shared__ float smem[2048];
    int bid = blockIdx.x, t = threadIdx.x;
    if (bid < NB_MM)
        do_mm(bid, t, ws);
    else if (bid < NB_MM + NB_SED)
        do_sed(bid - NB_MM, t, ws, smem);
    else
        do_recon(bid - NB_MM - NB_SED, t, (const unsigned long long*)rx,
                 (const unsigned long long*)x, ws, smem,
                 C1_START, C1_BLOCKS * 256, C0_BLOCKS);
}

// ---------------- dispatch 3: post || recon chunk2 ----------------
__global__ __launch_bounds__(256) void k_d3(const float* __restrict__ rx,
                                            const float* __restrict__ x,
                                            float* __restrict__ ws) {
    __shared__ float smem[256];
    int bid = blockIdx.x, t = threadIdx.x;
    if (bid < NB_POST)
        do_post(bid, t, ws);
    else
        do_recon(bid - NB_POST, t, (const unsigned long long*)rx,
                 (const unsigned long long*)x, ws, smem,
                 C2_START, C2_BLOCKS * 256, C0_BLOCKS + C1_BLOCKS);
}

// ---------------- dispatch 4: final combine (1 block) ----------------
__global__ __launch_bounds__(256) void k_final(const float* __restrict__ ws,
                                               float* __restrict__ out) {
    int t = threadIdx.x;
    float a0 = 0, a1 = 0, a2 = 0, a3 = 0, a4 = 0;
    for (int idx = t; idx < 1536; idx += 256) a0 += ws[WS_RP + idx];
    for (int idx = t; idx < BB; idx += 256) {
        a1 += ws[WS_LQC + idx];
        a2 += ws[WS_LPZ + idx];
        a3 += ws[WS_LQZ + idx];
        a4 += ws[WS_LPR + idx];
    }
    __shared__ float red[256];
    float vals[5] = {a0, a1, a2, a3, a4};
    float res[5];
    for (int q = 0; q < 5; q++) {
        red[t] = vals[q]; __syncthreads();
        for (int o = 128; o > 0; o >>= 1) {
            if (t < o) red[t] += red[t + o];
            __syncthreads();
        }
        res[q] = red[0]; __syncthreads();
    }
    if (t == 0) {
        float recon = res[0], slqc = res[1], slpz = res[2], slqz = res[3], slpr = res[4];
        out[0] = recon + (slqc + 5.f * (slqz - slpr) - slpz) * (1.0f / (float)BB);
    }
}

extern "C" void kernel_launch(void* const* d_in, const int* in_sizes, int n_in,
                              void* d_out, int out_size, void* d_ws, size_t ws_size,
                              hipStream_t stream) {
    (void)in_sizes; (void)n_in; (void)out_size; (void)ws_size;
    const float* rx = (const float*)d_in[0];
    const float* x  = (const float*)d_in[1];
    const float* mu = (const float*)d_in[2];
    const float* lv = (const float*)d_in[3];
    const float* nz = (const float*)d_in[4];
    float* ws  = (float*)d_ws;
    float* out = (float*)d_out;

    k_d1   <<<NB_PREP + C0_BLOCKS,          256, 0, stream>>>(rx, x, mu, lv, nz, ws);
    k_d2   <<<NB_MM + NB_SED + C1_BLOCKS,   256, 0, stream>>>(rx, x, ws);
    k_d3   <<<NB_POST + C2_BLOCKS,          256, 0, stream>>>(rx, x, ws);
    k_final<<<1, 256, 0, stream>>>(ws, out);
}